// Round 1
// baseline (77.642 us; speedup 1.0000x reference)
//
#include <hip/hip_runtime.h>
#include <hip/hip_bf16.h>

typedef __attribute__((ext_vector_type(8))) short bf16x8;
typedef __attribute__((ext_vector_type(4))) float f32x4;
typedef unsigned int uint32;

__device__ __forceinline__ unsigned short f2bf(float f) {
    unsigned int u = __float_as_uint(f);
    u = (u + 0x7FFFu + ((u >> 16) & 1u)) >> 16;
    return (unsigned short)u;
}
__device__ __forceinline__ float bf2f(uint32 h) {
    return __uint_as_float(h << 16);
}

// x: (8,128,64,64) fp32 NCHW -> xt: (8,64,64,128) bf16 NHWC
__global__ __launch_bounds__(256) void transpose_x(const float* __restrict__ x,
                                                   unsigned short* __restrict__ xt) {
    __shared__ float tile[32][33];
    int bi = blockIdx.x;
    int wb = bi & 1, cb = (bi >> 1) & 3, y = (bi >> 3) & 63, b = bi >> 9;
    int t = threadIdx.x;
    int lw = t & 31, lc = t >> 5;  // read: lanes along w (coalesced)
    #pragma unroll
    for (int pass = 0; pass < 4; ++pass) {
        int c = cb * 32 + lc + pass * 8;
        tile[lc + pass * 8][lw] = x[(((size_t)b * 128 + c) * 64 + y) * 64 + wb * 32 + lw];
    }
    __syncthreads();
    int cc = t & 31, xl = t >> 5;  // write: lanes along c (coalesced)
    #pragma unroll
    for (int pass = 0; pass < 4; ++pass) {
        int xll = xl + pass * 8;
        xt[(((size_t)b * 64 + y) * 64 + wb * 32 + xll) * 128 + cb * 32 + cc] =
            f2bf(tile[cc][xll]);
    }
}

// weight: (128F,128C,3,3) fp32 -> wT: [k][f][c] bf16
__global__ __launch_bounds__(256) void prep_w(const float* __restrict__ w,
                                              unsigned short* __restrict__ wT) {
    int idx = blockIdx.x * 256 + threadIdx.x;
    if (idx >= 9 * 128 * 128) return;
    int k = idx >> 14;
    int rem = idx & 16383;
    int f = rem >> 7, c = rem & 127;
    wT[idx] = f2bf(w[((size_t)f * 128 + c) * 9 + k]);
}

// Fused: per block = one (b, ho) output row (64 pixels) x all 128 F.
__global__ __launch_bounds__(256, 2) void dcn_main(
    const float* __restrict__ offset, const float* __restrict__ mask,
    const unsigned short* __restrict__ xt, const unsigned short* __restrict__ wT,
    float* __restrict__ out)
{
    __shared__ unsigned short cols[64][136];  // [pix][c padded to 136] bf16
    __shared__ float pw[9][64][4];            // corner weights * mask * validity
    __shared__ int   pc[9][64][4];            // y0c, y1c, x0c, x1c (clamped)

    int bi = blockIdx.x;
    int nb = (bi & 7) * 64 + (bi >> 3);  // XCD swizzle: batch b -> one XCD
    int b = nb >> 6, ho = nb & 63;

    int t = threadIdx.x, lane = t & 63, wid = t >> 6;

    // ---- Phase A: sampling params for all 9 taps x 64 pixels ----
    for (int task = t; task < 576; task += 256) {
        int k = task >> 6, p = task & 63;
        int ki = k / 3, kj = k % 3;
        float dy = offset[(((size_t)b * 18 + 2 * k)     * 64 + ho) * 64 + p];
        float dx = offset[(((size_t)b * 18 + 2 * k + 1) * 64 + ho) * 64 + p];
        float m  = mask  [(((size_t)b * 9  + k)         * 64 + ho) * 64 + p];
        float py = (float)(ho - 1 + ki) + dy;
        float px = (float)(p  - 1 + kj) + dx;
        float y0f = floorf(py), x0f = floorf(px);
        float ly = py - y0f, lx = px - x0f;
        float hy = 1.f - ly, hx = 1.f - lx;
        int y0 = (int)y0f, x0 = (int)x0f;
        int y1 = y0 + 1, x1 = x0 + 1;
        float vy0 = (y0 >= 0 && y0 < 64) ? 1.f : 0.f;
        float vy1 = (y1 >= 0 && y1 < 64) ? 1.f : 0.f;
        float vx0 = (x0 >= 0 && x0 < 64) ? 1.f : 0.f;
        float vx1 = (x1 >= 0 && x1 < 64) ? 1.f : 0.f;
        pw[k][p][0] = hy * hx * m * vy0 * vx0;
        pw[k][p][1] = hy * lx * m * vy0 * vx1;
        pw[k][p][2] = ly * hx * m * vy1 * vx0;
        pw[k][p][3] = ly * lx * m * vy1 * vx1;
        pc[k][p][0] = min(max(y0, 0), 63);
        pc[k][p][1] = min(max(y1, 0), 63);
        pc[k][p][2] = min(max(x0, 0), 63);
        pc[k][p][3] = min(max(x1, 0), 63);
    }
    __syncthreads();

    f32x4 acc[4][2];
    #pragma unroll
    for (int i = 0; i < 4; ++i)
        #pragma unroll
        for (int j = 0; j < 2; ++j) acc[i][j] = (f32x4){0.f, 0.f, 0.f, 0.f};

    const uint32* xb = (const uint32*)xt + (size_t)b * 64 * 64 * 64;  // 64 uints per (y,x)
    int wave_f = wid >> 1, wave_p = wid & 1;
    int l16 = lane & 15, lu = lane >> 4;

    for (int k = 0; k < 9; ++k) {
        // ---- gather: each wave handles 16 pixels; lane = channel pair ----
        #pragma unroll 4
        for (int pi = 0; pi < 16; ++pi) {
            int p = wid * 16 + pi;
            float w00 = pw[k][p][0], w01 = pw[k][p][1];
            float w10 = pw[k][p][2], w11 = pw[k][p][3];
            int y0c = pc[k][p][0], y1c = pc[k][p][1];
            int x0c = pc[k][p][2], x1c = pc[k][p][3];
            uint32 u00 = xb[(y0c * 64 + x0c) * 64 + lane];
            uint32 u01 = xb[(y0c * 64 + x1c) * 64 + lane];
            uint32 u10 = xb[(y1c * 64 + x0c) * 64 + lane];
            uint32 u11 = xb[(y1c * 64 + x1c) * 64 + lane];
            float f0 = w00 * bf2f(u00 & 0xffff) + w01 * bf2f(u01 & 0xffff)
                     + w10 * bf2f(u10 & 0xffff) + w11 * bf2f(u11 & 0xffff);
            float f1 = w00 * bf2f(u00 >> 16) + w01 * bf2f(u01 >> 16)
                     + w10 * bf2f(u10 >> 16) + w11 * bf2f(u11 >> 16);
            *(uint32*)&cols[p][2 * lane] = (uint32)f2bf(f0) | ((uint32)f2bf(f1) << 16);
        }
        __syncthreads();

        // ---- MFMA: block tile 128F x 64pix, K-step 32 over c ----
        const unsigned short* wTk = wT + k * 16384;
        #pragma unroll
        for (int ks = 0; ks < 4; ++ks) {
            int cbase = ks * 32 + lu * 8;
            bf16x8 a0 = *(const bf16x8*)(wTk + (wave_f * 64 + 0 * 16 + l16) * 128 + cbase);
            bf16x8 a1 = *(const bf16x8*)(wTk + (wave_f * 64 + 1 * 16 + l16) * 128 + cbase);
            bf16x8 a2 = *(const bf16x8*)(wTk + (wave_f * 64 + 2 * 16 + l16) * 128 + cbase);
            bf16x8 a3 = *(const bf16x8*)(wTk + (wave_f * 64 + 3 * 16 + l16) * 128 + cbase);
            bf16x8 b0 = *(const bf16x8*)&cols[wave_p * 32 + 0 * 16 + l16][cbase];
            bf16x8 b1 = *(const bf16x8*)&cols[wave_p * 32 + 1 * 16 + l16][cbase];
            acc[0][0] = __builtin_amdgcn_mfma_f32_16x16x32_bf16(a0, b0, acc[0][0], 0, 0, 0);
            acc[0][1] = __builtin_amdgcn_mfma_f32_16x16x32_bf16(a0, b1, acc[0][1], 0, 0, 0);
            acc[1][0] = __builtin_amdgcn_mfma_f32_16x16x32_bf16(a1, b0, acc[1][0], 0, 0, 0);
            acc[1][1] = __builtin_amdgcn_mfma_f32_16x16x32_bf16(a1, b1, acc[1][1], 0, 0, 0);
            acc[2][0] = __builtin_amdgcn_mfma_f32_16x16x32_bf16(a2, b0, acc[2][0], 0, 0, 0);
            acc[2][1] = __builtin_amdgcn_mfma_f32_16x16x32_bf16(a2, b1, acc[2][1], 0, 0, 0);
            acc[3][0] = __builtin_amdgcn_mfma_f32_16x16x32_bf16(a3, b0, acc[3][0], 0, 0, 0);
            acc[3][1] = __builtin_amdgcn_mfma_f32_16x16x32_bf16(a3, b1, acc[3][1], 0, 0, 0);
        }
        __syncthreads();
    }

    // ---- epilogue: D col = pix (lane&15), row = f via (lane>>4)*4 + r ----
    float* outb = out + ((size_t)b * 128 * 64 + ho) * 64;
    #pragma unroll
    for (int mf = 0; mf < 4; ++mf)
        #pragma unroll
        for (int np = 0; np < 2; ++np)
            #pragma unroll
            for (int r = 0; r < 4; ++r) {
                int f  = wave_f * 64 + mf * 16 + lu * 4 + r;
                int wo = wave_p * 32 + np * 16 + l16;
                outb[(size_t)f * 4096 + wo] = acc[mf][np][r];
            }
}

extern "C" void kernel_launch(void* const* d_in, const int* in_sizes, int n_in,
                              void* d_out, int out_size, void* d_ws, size_t ws_size,
                              hipStream_t stream) {
    const float* x      = (const float*)d_in[0];
    const float* offset = (const float*)d_in[1];
    const float* mask   = (const float*)d_in[2];
    const float* weight = (const float*)d_in[3];
    float* out = (float*)d_out;

    unsigned short* xt = (unsigned short*)d_ws;                 // 8*64*64*128 bf16 = 8 MiB
    unsigned short* wT = xt + (size_t)8 * 64 * 64 * 128;        // 9*128*128 bf16 = 288 KiB
    if (ws_size < (size_t)(8 * 64 * 64 * 128 + 9 * 128 * 128) * 2) return;

    transpose_x<<<4096, 256, 0, stream>>>(x, xt);
    prep_w<<<576, 256, 0, stream>>>(weight, wT);
    dcn_main<<<512, 256, 0, stream>>>(offset, mask, xt, wT, out);
}